// Round 12
// baseline (236.929 us; speedup 1.0000x reference)
//
#include <hip/hip_runtime.h>
#include <hip/hip_bf16.h>

typedef __bf16 bf16x8 __attribute__((ext_vector_type(8)));
typedef float f32x4 __attribute__((ext_vector_type(4)));

// Problem constants: B=2, S=2048, D=1024, H=16, HD=64
#define NB 2
#define NS 2048
#define ND 1024
#define NH 16
#define NHD 64

__device__ __forceinline__ unsigned short f2b(float f) {
    union { __hip_bfloat16 h; unsigned short u; } c;
    c.h = __float2bfloat16(f);
    return c.u;
}

// Async global->LDS, 16 bytes per lane. LDS dest = wave-uniform base + lane*16.
__device__ __forceinline__ void gl_lds16(const unsigned short* g, unsigned short* l) {
    __builtin_amdgcn_global_load_lds(
        (const __attribute__((address_space(1))) unsigned int*)g,
        (__attribute__((address_space(3))) unsigned int*)l, 16, 0, 0);
}

// ---------------------------------------------------------------------------
// One-shot f32->bf16 convert of x, Wq, Wk, Wv.
// ---------------------------------------------------------------------------
__global__ __launch_bounds__(256) void to_bf16_all(
    const float* __restrict__ x,  const float* __restrict__ wq,
    const float* __restrict__ wk, const float* __restrict__ wv,
    unsigned short* __restrict__ xb,  unsigned short* __restrict__ wqb,
    unsigned short* __restrict__ wkb, unsigned short* __restrict__ wvb)
{
    const size_t TX = (size_t)NB * NS * ND / 8;
    const size_t TW = (size_t)ND * ND / 8;
    size_t gid = (size_t)blockIdx.x * 256 + threadIdx.x;
    const float* src; unsigned short* dst; size_t off;
    if (gid < TX)               { src = x;  dst = xb;  off = gid * 8; }
    else if (gid < TX + TW)     { src = wq; dst = wqb; off = (gid - TX) * 8; }
    else if (gid < TX + 2 * TW) { src = wk; dst = wkb; off = (gid - TX - TW) * 8; }
    else                        { src = wv; dst = wvb; off = (gid - TX - 2 * TW) * 8; }
    float4 a = *(const float4*)(src + off);
    float4 b = *(const float4*)(src + off + 4);
    alignas(16) unsigned short t[8];
    t[0] = f2b(a.x); t[1] = f2b(a.y); t[2] = f2b(a.z); t[3] = f2b(a.w);
    t[4] = f2b(b.x); t[5] = f2b(b.y); t[6] = f2b(b.z); t[7] = f2b(b.w);
    *(uint4*)(dst + off) = *(const uint4*)t;
}

// ---------------------------------------------------------------------------
// Mask dtype probe. flag = 1 -> 4-byte elements, 0 -> 1-byte.
// ---------------------------------------------------------------------------
__global__ void detect_mask(const unsigned* __restrict__ m, int* __restrict__ flag) {
    __shared__ int bad;
    if (threadIdx.x == 0) bad = 0;
    __syncthreads();
    int mybad = 0;
    for (int i = threadIdx.x; i < 8192; i += 256) {
        unsigned w = m[i];
        if (w != 0u && w != 1u && w != 0x3F800000u) mybad = 1;
    }
    if (mybad) bad = 1;
    __syncthreads();
    if (threadIdx.x == 0) *flag = bad ? 0 : 1;
}

// ---------------------------------------------------------------------------
// Bit-pack the mask -> u64 words (1 MB, L2-resident).
// ---------------------------------------------------------------------------
__global__ __launch_bounds__(256) void pack_mask(
    const void* __restrict__ mask, const int* __restrict__ mflag,
    unsigned long long* __restrict__ mbits)
{
    const int wave = threadIdx.x >> 6;
    const int lane = threadIdx.x & 63;
    const size_t w = (size_t)blockIdx.x * 4 + wave;
    const size_t e = w * 64 + lane;
    int v;
    if (*mflag) v = (((const unsigned*)mask)[e] != 0u);
    else        v = (((const unsigned char*)mask)[e] != 0);
    unsigned long long bits = __ballot(v);
    if (lane == 0) mbits[w] = bits;
}

// ---------------------------------------------------------------------------
// QKV projection, m97 structure (128x128 tile, K-step 64) with COALESCED
// epilogue: Q/K transposed through per-wave LDS slot (reusing Alds/Blds)
// into 16B/lane dwordx4 stores; V packs 4 consecutive ss into dwordx2.
// Q output pre-scaled by log2e/sqrt(D) (softmax runs in exp2 domain).
// Q,K stored [B,H,S,HD] bf16; V stored transposed [B,H,HD,S] bf16.
// ---------------------------------------------------------------------------
__global__ __launch_bounds__(256) void qkv_gemm(
    const unsigned short* __restrict__ xb,
    const unsigned short* __restrict__ Wqb, const float* __restrict__ bq,
    const unsigned short* __restrict__ Wkb, const float* __restrict__ bk,
    const unsigned short* __restrict__ Wvb, const float* __restrict__ bv,
    unsigned short* __restrict__ Qb, unsigned short* __restrict__ Kb,
    unsigned short* __restrict__ Vtb)
{
    __shared__ alignas(16) unsigned short Alds[128 * 64];
    __shared__ alignas(16) unsigned short Blds[128 * 64];

    const int tid  = threadIdx.x;
    const int wave = tid >> 6;
    const int lane = tid & 63;
    const int z    = blockIdx.z;

    const unsigned short* W = (z == 0) ? Wqb : (z == 1) ? Wkb : Wvb;
    const float* bias       = (z == 0) ? bq  : (z == 1) ? bk  : bv;

    const int m0 = blockIdx.x * 128;
    const int n0 = blockIdx.y * 128;
    const int wr = (wave >> 1) * 64;
    const int wc = (wave & 1) * 64;

    // staging: instr i covers 16B-slots i*256+tid; slot s -> row=s>>3, seg=s&7
    int soff[4];
    #pragma unroll
    for (int i = 0; i < 4; i++) {
        const int r = i * 32 + (tid >> 3);
        soff[i] = r * ND + (((tid & 7) ^ (r & 7)) * 8);
    }

    const unsigned short* xsrc = xb + (size_t)m0 * ND;
    const unsigned short* wsrc = W  + (size_t)n0 * ND;

    const int lg = lane >> 4;
    const int ll = lane & 15;
    const int xr7 = ll & 7;

    f32x4 acc[4][4] = {};

    for (int kt = 0; kt < ND; kt += 64) {
        if (kt != 0) __syncthreads();
        #pragma unroll
        for (int i = 0; i < 4; i++) {
            gl_lds16(xsrc + kt + soff[i], Alds + i * 2048 + wave * 512);
            gl_lds16(wsrc + kt + soff[i], Blds + i * 2048 + wave * 512);
        }
        __syncthreads();   // vmcnt(0) drained by compiler before barrier

        #pragma unroll
        for (int kk = 0; kk < 2; kk++) {
            const int segb = ((kk * 4 + lg) ^ xr7) * 16;
            bf16x8 af[4], bfr[4];
            #pragma unroll
            for (int m = 0; m < 4; m++)
                af[m] = *(const bf16x8*)((const char*)Alds
                         + (wr + m * 16 + ll) * 128 + segb);
            #pragma unroll
            for (int n = 0; n < 4; n++)
                bfr[n] = *(const bf16x8*)((const char*)Blds
                         + (wc + n * 16 + ll) * 128 + segb);

            #pragma unroll
            for (int m = 0; m < 4; m++)
                #pragma unroll
                for (int n = 0; n < 4; n++)
                    acc[m][n] = __builtin_amdgcn_mfma_f32_16x16x32_bf16(
                        af[m], bfr[n], acc[m][n], 0, 0, 0);
        }
    }

    if (z == 2) {
        // V^T epilogue: acc r-index = 4 consecutive ss -> pack to dwordx2.
        #pragma unroll
        for (int n = 0; n < 4; n++) {
            const int j = n0 + wc + n * 16 + ll;
            const float bj = bias[j];
            const int hh = j >> 6, hd = j & 63;
            #pragma unroll
            for (int m = 0; m < 4; m++) {
                const int i = m0 + wr + m * 16 + lg * 4;
                const int bb = i >> 11, sI = i & 2047;
                alignas(8) unsigned short t4[4];
                #pragma unroll
                for (int r = 0; r < 4; r++) t4[r] = f2b(acc[m][n][r] + bj);
                *(uint2*)&Vtb[((size_t)(bb * NH + hh) * NHD + hd) * NS + sI] =
                    *(const uint2*)t4;
            }
        }
    } else {
        // Q/K epilogue: per-wave LDS transpose -> coalesced dwordx4 stores.
        const float oscale = (z == 0) ? 0.045084253f : 1.0f;  // log2e/sqrt(D)
        __syncthreads();   // all waves done with Alds/Blds MFMA reads
        unsigned short* scr = ((wave & 2) ? Blds : Alds) + (wave & 1) * 4096;
        #pragma unroll
        for (int n = 0; n < 4; n++) {
            const int col = n * 16 + ll;
            const float bj = bias[n0 + wc + col];
            #pragma unroll
            for (int m = 0; m < 4; m++)
                #pragma unroll
                for (int r = 0; r < 4; r++)
                    scr[(m * 16 + lg * 4 + r) * 64 + col] =
                        f2b((acc[m][n][r] + bj) * oscale);
        }
        // same-wave LDS write->read: LDS pipe processes wave ops in order
        const int rr = lane >> 3, c8 = (lane & 7) * 8;
        const int hh = (n0 + wc) >> 6;   // 64-col block = exactly one head
        unsigned short* dst = (z == 0) ? Qb : Kb;
        #pragma unroll
        for (int i = 0; i < 8; i++) {
            const int row = i * 8 + rr;
            uint4 v = *(const uint4*)&scr[row * 64 + c8];
            const int gi = m0 + wr + row;
            const int bb = gi >> 11, sI = gi & 2047;
            *(uint4*)&dst[((size_t)(bb * NH + hh) * NS + sI) * NHD + c8] = v;
        }
    }
}

// ---------------------------------------------------------------------------
// Flash attention, 8-wave blocks, DOUBLE-BUFFERED LDS K/V tiles: stage t+1
// issued before compute t, single barrier per chunk -> staging latency hides
// under softmax+PV. Softmax in exp2 domain (log2e folded into Q).
// ---------------------------------------------------------------------------
__global__ __launch_bounds__(512, 4) void attn_kernel(
    const unsigned short* __restrict__ Qb, const unsigned short* __restrict__ Kb,
    const unsigned short* __restrict__ Vtb,
    const unsigned long long* __restrict__ mbits, float* __restrict__ out)
{
    __shared__ alignas(16) unsigned short Kt[2][64 * 64];
    __shared__ alignas(16) unsigned short Vt[2][64 * 64];
    __shared__ alignas(16) unsigned short Plds[8][16][72];

    const int tid  = threadIdx.x;
    const int wave = tid >> 6;
    const int lane = tid & 63;

    // XCD-bijective decode: 512 wgs, 4 heads per XCD, 16 q-blocks per head.
    const int wg   = blockIdx.x;
    const int xcd  = wg & 7;
    const int slot = wg >> 3;                // 0..63
    const int hb   = xcd * 4 + (slot >> 4);  // 0..31
    const int qblk = slot & 15;
    const int h = hb & (NH - 1);
    const int b = hb >> 4;
    const int q0 = qblk * 128 + wave * 16;

    const unsigned short* Qp = Qb  + (size_t)(b * NH + h) * NS * NHD;
    const unsigned short* Kp = Kb  + (size_t)(b * NH + h) * NS * NHD;
    const unsigned short* Vp = Vtb + (size_t)(b * NH + h) * NHD * NS;
    const unsigned long long* mrow = mbits + (size_t)b * NS * (NS / 64);

    const int lg = lane >> 4;
    const int ll = lane & 15;

    // staging invariants: this lane stages tile row rw, source seg pre-swizzled
    const int rw = wave * 8 + (lane >> 3);
    const int sg = (lane & 7) ^ (rw & 7);
    const size_t ksoff = (size_t)rw * NHD + sg * 8;
    const size_t vsoff = (size_t)rw * NS  + sg * 8;

    // frag-read byte offsets within a tile (row ll-based, XOR-deswizzled)
    const int xr7 = ll & 7;
    const int ka0 = ll * 128 + ((lg)     ^ xr7) * 16;   // k/d segs 0..31
    const int ka1 = ll * 128 + ((lg + 4) ^ xr7) * 16;   // segs 32..63

    // Q fragments (B-operand), hoisted; Q is pre-scaled by log2e/sqrt(D)
    const int kcol = lg * 8;
    const bf16x8 qf0 = *(const bf16x8*)&Qp[(q0 + ll) * NHD + kcol];
    const bf16x8 qf1 = *(const bf16x8*)&Qp[(q0 + ll) * NHD + 32 + kcol];

    f32x4 O0 = {}, O1 = {}, O2 = {}, O3 = {};
    float mrun = -3.0e38f;   // running max (log2 domain) for q = q0 + ll
    float lrun = 0.f;

    unsigned long long mwc = mrow[(size_t)(q0 + ll) * (NS / 64)];

    // ---- prologue: stage chunk 0 ----
    gl_lds16(Kp + ksoff, Kt[0] + wave * 512);
    gl_lds16(Vp + vsoff, Vt[0] + wave * 512);
    __syncthreads();

    for (int t = 0; t < 32; t++) {
        const int kb = t * 64;
        const int cur = t & 1;

        // ---- stage chunk t+1 into the other buffer (no wait) ----
        if (t + 1 < 32) {
            gl_lds16(Kp + (size_t)(kb + 64) * NHD + ksoff, Kt[cur ^ 1] + wave * 512);
            gl_lds16(Vp + (kb + 64) + vsoff, Vt[cur ^ 1] + wave * 512);
        }
        const int tn = (t + 1 < 32) ? t + 1 : 0;
        const unsigned long long mwn = mrow[(size_t)(q0 + ll) * (NS / 64) + tn];

        // ---- K fragments from LDS, QK^T swapped ----
        const char* Kc = (const char*)Kt[cur];
        const char* Vc = (const char*)Vt[cur];
        f32x4 s0 = {}, s1 = {}, s2 = {}, s3 = {};
        {
            const bf16x8 k00 = *(const bf16x8*)(Kc + 0 * 2048 + ka0);
            const bf16x8 k10 = *(const bf16x8*)(Kc + 1 * 2048 + ka0);
            const bf16x8 k20 = *(const bf16x8*)(Kc + 2 * 2048 + ka0);
            const bf16x8 k30 = *(const bf16x8*)(Kc + 3 * 2048 + ka0);
            s0 = __builtin_amdgcn_mfma_f32_16x16x32_bf16(k00, qf0, s0, 0, 0, 0);
            s1 = __builtin_amdgcn_mfma_f32_16x16x32_bf16(k10, qf0, s1, 0, 0, 0);
            s2 = __builtin_amdgcn_mfma_f32_16x16x32_bf16(k20, qf0, s2, 0, 0, 0);
            s3 = __builtin_amdgcn_mfma_f32_16x16x32_bf16(k30, qf0, s3, 0, 0, 0);
            const bf16x8 k01 = *(const bf16x8*)(Kc + 0 * 2048 + ka1);
            const bf16x8 k11 = *(const bf16x8*)(Kc + 1 * 2048 + ka1);
            const bf16x8 k21 = *(const bf16x8*)(Kc + 2 * 2048 + ka1);
            const bf16x8 k31 = *(const bf16x8*)(Kc + 3 * 2048 + ka1);
            s0 = __builtin_amdgcn_mfma_f32_16x16x32_bf16(k01, qf1, s0, 0, 0, 0);
            s1 = __builtin_amdgcn_mfma_f32_16x16x32_bf16(k11, qf1, s1, 0, 0, 0);
            s2 = __builtin_amdgcn_mfma_f32_16x16x32_bf16(k21, qf1, s2, 0, 0, 0);
            s3 = __builtin_amdgcn_mfma_f32_16x16x32_bf16(k31, qf1, s3, 0, 0, 0);
        }

        // ---- scores (log2 domain): sv[tt*4+r], k = kb+16tt+4lg+r ----
        const unsigned long long mws = mwc >> (lg * 4);
        float sv[16];
        #pragma unroll
        for (int tt = 0; tt < 4; tt++) {
            const f32x4 st = (tt == 0) ? s0 : (tt == 1) ? s1 : (tt == 2) ? s2 : s3;
            #pragma unroll
            for (int r = 0; r < 4; r++)
                sv[tt * 4 + r] = ((mws >> (16 * tt + r)) & 1ull) ? -1e9f : st[r];
        }

        float m01 = fmaxf(fmaxf(sv[0], sv[1]), fmaxf(sv[2], sv[3]));
        float m23 = fmaxf(fmaxf(sv[4], sv[5]), fmaxf(sv[6], sv[7]));
        float m45 = fmaxf(fmaxf(sv[8], sv[9]), fmaxf(sv[10], sv[11]));
        float m67 = fmaxf(fmaxf(sv[12], sv[13]), fmaxf(sv[14], sv[15]));
        float mt = fmaxf(fmaxf(m01, m23), fmaxf(m45, m67));
        mt = fmaxf(mt, __shfl_xor(mt, 16));
        mt = fmaxf(mt, __shfl_xor(mt, 32));

        if (!__all(mt <= mrun + 8.0f)) {
            const float mnew  = fmaxf(mrun, mt);
            const float alpha = exp2f(mrun - mnew);
            mrun = mnew;
            lrun *= alpha;
            #pragma unroll
            for (int r = 0; r < 4; r++) {
                const float ar = __shfl(alpha, lg * 4 + r);
                O0[r] *= ar; O1[r] *= ar; O2[r] *= ar; O3[r] *= ar;
            }
        }

        // ---- exp2 + sum + pack P ----
        float rs = 0.f;
        #pragma unroll
        for (int tt = 0; tt < 4; tt++) {
            const float p0 = exp2f(sv[tt * 4 + 0] - mrun);
            const float p1 = exp2f(sv[tt * 4 + 1] - mrun);
            const float p2 = exp2f(sv[tt * 4 + 2] - mrun);
            const float p3 = exp2f(sv[tt * 4 + 3] - mrun);
            rs += (p0 + p1) + (p2 + p3);
            uint2 w;
            w.x = (unsigned)f2b(p0) | ((unsigned)f2b(p1) << 16);
            w.y = (unsigned)f2b(p2) | ((unsigned)f2b(p3) << 16);
            *(uint2*)&Plds[wave][ll][tt * 16 + lg * 4] = w;
        }
        rs += __shfl_xor(rs, 16);
        rs += __shfl_xor(rs, 32);
        lrun += rs;

        // ---- PV: A = P from per-wave LDS slice, B = V^T frags from tile ----
        const bf16x8 pa0 = *(const bf16x8*)&Plds[wave][ll][kcol];
        const bf16x8 pa1 = *(const bf16x8*)&Plds[wave][ll][32 + kcol];
        {
            const bf16x8 v00 = *(const bf16x8*)(Vc + 0 * 2048 + ka0);
            const bf16x8 v10 = *(const bf16x8*)(Vc + 1 * 2048 + ka0);
            const bf16x8 v20 = *(const bf16x8*)(Vc + 2 * 2048 + ka0);
            const bf16x8 v30 = *(const bf16x8*)(Vc + 3 * 2048 + ka0);
            O0 = __builtin_amdgcn_mfma_f32_16x16x32_bf16(pa0, v00, O0, 0, 0, 0);
            O1 = __builtin_amdgcn_mfma_f32_16x16x32_bf16(pa0, v10, O1, 0, 0, 0);
            O2 = __builtin_amdgcn_mfma_f32_16x16x32_bf16(pa0, v20, O2, 0, 0, 0);
            O3 = __builtin_amdgcn_mfma_f32_16x16x32_bf16(pa0, v30, O3, 0, 0, 0);
            const bf16x8 v01 = *(const bf16x8*)(Vc + 0 * 2048 + ka1);
            const bf16x8 v11 = *(const bf16x8*)(Vc + 1 * 2048 + ka1);
            const bf16x8 v21 = *(const bf16x8*)(Vc + 2 * 2048 + ka1);
            const bf16x8 v31 = *(const bf16x8*)(Vc + 3 * 2048 + ka1);
            O0 = __builtin_amdgcn_mfma_f32_16x16x32_bf16(pa1, v01, O0, 0, 0, 0);
            O1 = __builtin_amdgcn_mfma_f32_16x16x32_bf16(pa1, v11, O1, 0, 0, 0);
            O2 = __builtin_amdgcn_mfma_f32_16x16x32_bf16(pa1, v21, O2, 0, 0, 0);
            O3 = __builtin_amdgcn_mfma_f32_16x16x32_bf16(pa1, v31, O3, 0, 0, 0);
        }

        __syncthreads();   // drains vmcnt (stage t+1 done) + guards buf reuse
        mwc = mwn;
    }

    #pragma unroll
    for (int r = 0; r < 4; r++) {
        const int q = q0 + lg * 4 + r;
        const float inv = 1.0f / __shfl(lrun, lg * 4 + r);
        float* op = out + (size_t)(b * NS + q) * ND + h * NHD;
        op[0 * 16 + ll] = O0[r] * inv;
        op[1 * 16 + ll] = O1[r] * inv;
        op[2 * 16 + ll] = O2[r] * inv;
        op[3 * 16 + ll] = O3[r] * inv;
    }
}

extern "C" void kernel_launch(void* const* d_in, const int* in_sizes, int n_in,
                              void* d_out, int out_size, void* d_ws, size_t ws_size,
                              hipStream_t stream)
{
    const float* x  = (const float*)d_in[0];
    const void* mask = d_in[1];
    const float* Wq = (const float*)d_in[2];
    const float* bq = (const float*)d_in[3];
    const float* Wk = (const float*)d_in[4];
    const float* bk = (const float*)d_in[5];
    const float* Wv = (const float*)d_in[6];
    const float* bv = (const float*)d_in[7];
    float* out = (float*)d_out;

    const size_t szX = (size_t)NB * NS * ND;
    const size_t szW = (size_t)ND * ND;
    const size_t szQ = (size_t)NB * NH * NS * NHD;

    int* mflag = (int*)d_ws;
    unsigned short* xb  = (unsigned short*)((char*)d_ws + 256);
    unsigned short* Wqb = xb  + szX;
    unsigned short* Wkb = Wqb + szW;
    unsigned short* Wvb = Wkb + szW;
    unsigned short* Qb  = Wvb + szW;
    unsigned short* Kb  = Qb + szQ;
    unsigned short* Vtb = Kb + szQ;
    unsigned long long* mbits = (unsigned long long*)(Vtb + szQ);

    dim3 blk(256);
    const int cvtBlocks = (int)((szX + 3 * szW) / 8 / 256);
    to_bf16_all<<<dim3(cvtBlocks), blk, 0, stream>>>(
        x, Wq, Wk, Wv, xb, Wqb, Wkb, Wvb);

    detect_mask<<<dim3(1), blk, 0, stream>>>((const unsigned*)mask, mflag);
    const int words = NB * NS * NS / 64;
    pack_mask<<<dim3(words / 4), blk, 0, stream>>>(mask, mflag, mbits);

    dim3 g1(32, 8, 3);
    qkv_gemm<<<g1, blk, 0, stream>>>(xb, Wqb, bq, Wkb, bk, Wvb, bv, Qb, Kb, Vtb);

    attn_kernel<<<dim3(512), dim3(512), 0, stream>>>(Qb, Kb, Vtb, mbits, out);
}